// Round 6
// baseline (447.110 us; speedup 1.0000x reference)
//
#include <hip/hip_runtime.h>
#include <stdint.h>

typedef __bf16 bf16;
typedef __bf16 bf16x8 __attribute__((ext_vector_type(8)));
typedef __bf16 bf16x4 __attribute__((ext_vector_type(4)));
typedef float  f32x4  __attribute__((ext_vector_type(4)));

#define BATCH    65536
#define NCAT     640      // 599 spline logits + a + b, padded to 640
#define SPSTRIDE 604      // sp row stride in elements

#define MFMA __builtin_amdgcn_mfma_f32_16x16x32_bf16

// ---------------------------------------------------------------------------
// Kernel 0: weights -> bf16; Wcat[640][512] = [WV; Wa; Wb; 0]; inputs -> bf16
// ---------------------------------------------------------------------------
__global__ __launch_bounds__(256) void prep_kernel(
    const float* W1, const float* W2, const float* WV,
    const float* bV, const float* Wa, const float* ba,
    const float* Wb, const float* bb, const float* inputs,
    bf16* w1b, bf16* w2b, bf16* wcat, float* bcat, bf16* xin)
{
    int idx = blockIdx.x * 256 + threadIdx.x;
    const int n1 = 512 * 128, n2 = 512 * 512, n3 = NCAT * 512;
    const int n5 = BATCH * 128 / 8;                 // 8 floats per item
    if (idx < n5) {                                  // input cast (bulk) first
        const float4* src = (const float4*)(inputs + idx * 8);
        float4 v0 = src[0], v1 = src[1];
        bf16x8 h;
        h[0]=(bf16)v0.x; h[1]=(bf16)v0.y; h[2]=(bf16)v0.z; h[3]=(bf16)v0.w;
        h[4]=(bf16)v1.x; h[5]=(bf16)v1.y; h[6]=(bf16)v1.z; h[7]=(bf16)v1.w;
        *(bf16x8*)&xin[idx * 8] = h;
        return;
    }
    idx -= n5;
    if (idx < n1) { w1b[idx] = (bf16)W1[idx]; return; }
    idx -= n1;
    if (idx < n2) { w2b[idx] = (bf16)W2[idx]; return; }
    idx -= n2;
    if (idx < n3) {
        int n = idx >> 9, k = idx & 511;
        float v = 0.f;
        if (n < 599)       v = WV[n * 512 + k];
        else if (n == 599) v = Wa[k];
        else if (n == 600) v = Wb[k];
        wcat[idx] = (bf16)v;
        return;
    }
    idx -= n3;
    if (idx < NCAT) {
        float v = 0.f;
        if (idx < 599)       v = bV[idx];
        else if (idx == 599) v = ba[0];
        else if (idx == 600) v = bb[0];
        bcat[idx] = v;
    }
}

// ---------------------------------------------------------------------------
// Fused MLP: per 64-row block, barrier-free K-loops, operands direct from L2.
//   G1: X1 = relu(LN(xin @ W1^T + b1)) -> LDS (XOR-swizzled, never HBM)
//   G2: X2 = relu(LN(X1 @ W2^T + b2))  -> dense bf16 store to x
// 8 waves 2Mx4N, wave tile 32x128 (acc[2][8], 16 MFMA/K-step).
// ---------------------------------------------------------------------------
__global__ __launch_bounds__(512) void fused_mlp(
    const bf16* __restrict__ xin, const bf16* __restrict__ w1,
    const float* __restrict__ b1, const float* __restrict__ g1,
    const float* __restrict__ be1,
    const bf16* __restrict__ w2,
    const float* __restrict__ b2, const float* __restrict__ g2,
    const float* __restrict__ be2,
    bf16* __restrict__ xout)
{
    __shared__ __align__(16) char X1[65536];     // X1 swizzled; later X2 stage
    __shared__ float Psum[64][4], Psq[64][4];

    const int t = threadIdx.x;
    const int lane = t & 63, wid = t >> 6;
    const int wm = wid >> 2, wn = wid & 3;
    const int l16 = lane & 15, g16 = lane >> 4;
    const long row0 = (long)blockIdx.x * 64;

    f32x4 acc[2][8];
#pragma unroll
    for (int a = 0; a < 2; ++a)
#pragma unroll
        for (int b = 0; b < 8; ++b) acc[a][b] = (f32x4){0.f, 0.f, 0.f, 0.f};

    // ================= G1: K=128, A/B direct from global =================
#pragma unroll
    for (int kt = 0; kt < 4; ++kt) {
        const int ka = kt * 32 + g16 * 8;
        bf16x8 af0 = *(const bf16x8*)&xin[(row0 + wm * 32 + l16) * 128 + ka];
        bf16x8 af1 = *(const bf16x8*)&xin[(row0 + wm * 32 + 16 + l16) * 128 + ka];
#pragma unroll
        for (int fn = 0; fn < 8; ++fn) {
            bf16x8 bv = *(const bf16x8*)&w1[(wn * 128 + fn * 16 + l16) * 128 + ka];
            acc[0][fn] = MFMA(af0, bv, acc[0][fn], 0, 0, 0);
            acc[1][fn] = MFMA(af1, bv, acc[1][fn], 0, 0, 0);
        }
    }

    // ---- LN1 + ReLU -> X1 (swizzled scalar stores) ----
#pragma unroll
    for (int fm = 0; fm < 2; ++fm)
#pragma unroll
        for (int fn = 0; fn < 8; ++fn) {
            float bv = b1[wn * 128 + fn * 16 + l16];
#pragma unroll
            for (int i = 0; i < 4; ++i) acc[fm][fn][i] += bv;
        }
#pragma unroll
    for (int fm = 0; fm < 2; ++fm)
#pragma unroll
        for (int i = 0; i < 4; ++i) {
            float s = 0.f, q = 0.f;
#pragma unroll
            for (int fn = 0; fn < 8; ++fn) { float v = acc[fm][fn][i]; s += v; q += v * v; }
#pragma unroll
            for (int m = 1; m < 16; m <<= 1) { s += __shfl_xor(s, m); q += __shfl_xor(q, m); }
            if (l16 == 0) {
                int lr = wm * 32 + fm * 16 + g16 * 4 + i;
                Psum[lr][wn] = s; Psq[lr][wn] = q;
            }
        }
    __syncthreads();
#pragma unroll
    for (int fm = 0; fm < 2; ++fm)
#pragma unroll
        for (int i = 0; i < 4; ++i) {
            int lr = wm * 32 + fm * 16 + g16 * 4 + i;
            float s = Psum[lr][0] + Psum[lr][1] + Psum[lr][2] + Psum[lr][3];
            float q = Psq[lr][0] + Psq[lr][1] + Psq[lr][2] + Psq[lr][3];
            float mean = s * (1.f / 512.f);
            float var  = q * (1.f / 512.f) - mean * mean;
            float rstd = rsqrtf(var + 1e-5f);
#pragma unroll
            for (int fn = 0; fn < 8; ++fn) {
                int col = wn * 128 + fn * 16 + l16;
                float o = (acc[fm][fn][i] - mean) * rstd * g1[col] + be1[col];
                uint32_t off = (uint32_t)(lr * 1024 + col * 2) ^ (uint32_t)((lr & 7) << 4);
                *(bf16*)(X1 + off) = (bf16)fmaxf(o, 0.f);
            }
        }
    __syncthreads();   // X1 ready for all waves

    // ================= G2: K=512, A from LDS (swizzled), B direct =========
#pragma unroll
    for (int a = 0; a < 2; ++a)
#pragma unroll
        for (int b = 0; b < 8; ++b) acc[a][b] = (f32x4){0.f, 0.f, 0.f, 0.f};

    const int r0 = wm * 32 + l16, r1 = r0 + 16;
    const uint32_t sw0 = (uint32_t)((r0 & 7) << 4), sw1 = (uint32_t)((r1 & 7) << 4);
#pragma unroll 4
    for (int kt = 0; kt < 16; ++kt) {
        bf16x8 af0 = *(const bf16x8*)(X1 + ((uint32_t)(r0 * 1024 + kt * 64 + g16 * 16) ^ sw0));
        bf16x8 af1 = *(const bf16x8*)(X1 + ((uint32_t)(r1 * 1024 + kt * 64 + g16 * 16) ^ sw1));
#pragma unroll
        for (int fn = 0; fn < 8; ++fn) {
            bf16x8 bv = *(const bf16x8*)&w2[(wn * 128 + fn * 16 + l16) * 512 + kt * 32 + g16 * 8];
            acc[0][fn] = MFMA(af0, bv, acc[0][fn], 0, 0, 0);
            acc[1][fn] = MFMA(af1, bv, acc[1][fn], 0, 0, 0);
        }
    }

    // ---- LN2 + ReLU -> linear stage (over X1) -> dense store ----
#pragma unroll
    for (int fm = 0; fm < 2; ++fm)
#pragma unroll
        for (int fn = 0; fn < 8; ++fn) {
            float bv = b2[wn * 128 + fn * 16 + l16];
#pragma unroll
            for (int i = 0; i < 4; ++i) acc[fm][fn][i] += bv;
        }
#pragma unroll
    for (int fm = 0; fm < 2; ++fm)
#pragma unroll
        for (int i = 0; i < 4; ++i) {
            float s = 0.f, q = 0.f;
#pragma unroll
            for (int fn = 0; fn < 8; ++fn) { float v = acc[fm][fn][i]; s += v; q += v * v; }
#pragma unroll
            for (int m = 1; m < 16; m <<= 1) { s += __shfl_xor(s, m); q += __shfl_xor(q, m); }
            if (l16 == 0) {
                int lr = wm * 32 + fm * 16 + g16 * 4 + i;
                Psum[lr][wn] = s; Psq[lr][wn] = q;
            }
        }
    __syncthreads();   // also: all waves done reading X1 (G2 loop)
    bf16* stg = (bf16*)X1;
#pragma unroll
    for (int fm = 0; fm < 2; ++fm)
#pragma unroll
        for (int i = 0; i < 4; ++i) {
            int lr = wm * 32 + fm * 16 + g16 * 4 + i;
            float s = Psum[lr][0] + Psum[lr][1] + Psum[lr][2] + Psum[lr][3];
            float q = Psq[lr][0] + Psq[lr][1] + Psq[lr][2] + Psq[lr][3];
            float mean = s * (1.f / 512.f);
            float var  = q * (1.f / 512.f) - mean * mean;
            float rstd = rsqrtf(var + 1e-5f);
#pragma unroll
            for (int fn = 0; fn < 8; ++fn) {
                int col = wn * 128 + fn * 16 + l16;
                float o = (acc[fm][fn][i] - mean) * rstd * g2[col] + be2[col];
                stg[lr * 512 + col] = (bf16)fmaxf(o, 0.f);
            }
        }
    __syncthreads();
#pragma unroll
    for (int i = 0; i < 8; ++i) {                 // 64 rows x 1KB, dense
        int idx = i * 512 + t;
        *(bf16x8*)&xout[(row0 + (idx >> 6)) * 512 + (idx & 63) * 8] =
            *(const bf16x8*)&stg[idx * 8];
    }
}

// ---------------------------------------------------------------------------
// G3: sp[64 x 640] = X2[64 x 512] @ Wcat^T + bcat. Operands direct from L2,
// barrier-free K-loop; 8 waves 2Mx4N, wave tile 32x160 (acc[2][10]).
// Output staged in LDS -> dense 8B writeout (stride-604 rows); ab f32 direct.
// ---------------------------------------------------------------------------
__global__ __launch_bounds__(512) void gemm_cat(
    const bf16* __restrict__ A, const bf16* __restrict__ W,
    const float* __restrict__ bcat, bf16* __restrict__ sp, float* __restrict__ ab)
{
    __shared__ __align__(16) bf16 stg[64 * SPSTRIDE];   // 77312 B

    const int t = threadIdx.x;
    const int lane = t & 63, wid = t >> 6;
    const int wm = wid >> 2, wn = wid & 3;
    const int l16 = lane & 15, g16 = lane >> 4;
    const long row0 = (long)blockIdx.x * 64;

    f32x4 acc[2][10];
#pragma unroll
    for (int a = 0; a < 2; ++a)
#pragma unroll
        for (int b = 0; b < 10; ++b) acc[a][b] = (f32x4){0.f, 0.f, 0.f, 0.f};

#pragma unroll 4
    for (int kt = 0; kt < 16; ++kt) {
        const int ka = kt * 32 + g16 * 8;
        bf16x8 af0 = *(const bf16x8*)&A[(row0 + wm * 32 + l16) * 512 + ka];
        bf16x8 af1 = *(const bf16x8*)&A[(row0 + wm * 32 + 16 + l16) * 512 + ka];
#pragma unroll
        for (int fn = 0; fn < 10; ++fn) {
            bf16x8 bv = *(const bf16x8*)&W[(wn * 160 + fn * 16 + l16) * 512 + ka];
            acc[0][fn] = MFMA(af0, bv, acc[0][fn], 0, 0, 0);
            acc[1][fn] = MFMA(af1, bv, acc[1][fn], 0, 0, 0);
        }
    }

    // ---- epilogue: +bcat -> LDS stage [64][604]; ab f32 direct ----
#pragma unroll
    for (int fn = 0; fn < 10; ++fn) {
        int col = wn * 160 + fn * 16 + l16;
        float bv = bcat[col];
#pragma unroll
        for (int fm = 0; fm < 2; ++fm)
#pragma unroll
            for (int i = 0; i < 4; ++i) {
                int r = wm * 32 + fm * 16 + g16 * 4 + i;
                float v = acc[fm][fn][i] + bv;
                if (col < SPSTRIDE) stg[r * SPSTRIDE + col] = (bf16)v;
                if (col == 599)      ab[(row0 + r) * 2 + 0] = v;
                else if (col == 600) ab[(row0 + r) * 2 + 1] = v;
            }
    }
    __syncthreads();
    for (int c = t; c < 64 * 151; c += 512) {     // 151 x 8B chunks per row
        int r = c / 151, k = c - r * 151;
        *(uint64_t*)&sp[(row0 + r) * SPSTRIDE + k * 4] =
            *(const uint64_t*)&stg[r * SPSTRIDE + k * 4];
    }
}

// ---------------------------------------------------------------------------
// Spline v3: register scan -> LDS param tables -> binidx scatter ->
// balanced gather (lane computes exactly 4 outputs j = lane + 50k).
// ---------------------------------------------------------------------------
__global__ __launch_bounds__(256) void spline_kernel(
    const bf16* __restrict__ sp, const float* __restrict__ ab, float* __restrict__ out)
{
    __shared__ float S[4][816];     // per wave: cw@0, ch@204, dd@408, binidx@612
    const int t = threadIdx.x;
    const int lane = t & 63, wid = t >> 6;
    const long row = (long)blockIdx.x * 4 + wid;
    const bf16* spr = sp + row * SPSTRIDE;
    const bool act = lane < 50;
    const float EC = 0.53974247f;                 // log(exp(0.999)-1)
    float* cw = &S[wid][0];
    float* ch = &S[wid][204];
    float* dd = &S[wid][408];
    int*   bx = (int*)&S[wid][612];

    const float sa = __expf(ab[row * 2 + 0]);
    const float sb = ab[row * 2 + 1];

    auto rng = [](float x) -> int {               // first j with tau_j >= x
        int v = (int)ceilf(fmaf(200.f, x, -0.5f));
        return v < 0 ? 0 : (v > 200 ? 200 : v);
    };

    // ---- W logits -> widths -> cw[4l..4l+3] in regs ----
    float p0, p1, p2, p3;
    {
        float x0, x1, x2v, x3;
        if (act) {
            bf16x4 v = *(const bf16x4*)&spr[4 * lane];
            x0 = (float)v[0]; x1 = (float)v[1]; x2v = (float)v[2]; x3 = (float)v[3];
        } else { x0 = x1 = x2v = x3 = -1e30f; }
        float m = fmaxf(fmaxf(x0, x1), fmaxf(x2v, x3));
#pragma unroll
        for (int d = 1; d < 64; d <<= 1) m = fmaxf(m, __shfl_xor(m, d));
        float e0 = act ? __expf(x0 - m) : 0.f;
        float e1 = act ? __expf(x1 - m) : 0.f;
        float e2 = act ? __expf(x2v - m) : 0.f;
        float e3 = act ? __expf(x3 - m) : 0.f;
        float s = e0 + e1 + e2 + e3;
#pragma unroll
        for (int d = 1; d < 64; d <<= 1) s += __shfl_xor(s, d);
        float inv = 0.8f / s;
        p0 = act ? fmaf(e0, inv, 0.001f) : 0.f;
        p1 = act ? fmaf(e1, inv, 0.001f) : 0.f;
        p2 = act ? fmaf(e2, inv, 0.001f) : 0.f;
        p3 = act ? fmaf(e3, inv, 0.001f) : 0.f;
    }
    float c0 = p0, c1 = c0 + p1, c2 = c1 + p2, c3 = c2 + p3;
    float run = c3, ts = run;
#pragma unroll
    for (int d = 1; d < 64; d <<= 1) { float u = __shfl_up(ts, d); if (lane >= d) ts += u; }
    float excl  = ts - run;
    float nexcl = __shfl_down(excl, 1);
    float cwl0 = excl, cwl1 = excl + c0, cwl2 = excl + c1, cwl3 = excl + c2;

    // ---- H logits -> heights -> ch[4l..4l+3] ----
    float hp0, hp1, hp2, hp3;
    {
        float x0, x1, x2v, x3;
        if (act) {
            bf16x4 v = *(const bf16x4*)&spr[200 + 4 * lane];
            x0 = (float)v[0]; x1 = (float)v[1]; x2v = (float)v[2]; x3 = (float)v[3];
        } else { x0 = x1 = x2v = x3 = -1e30f; }
        float m = fmaxf(fmaxf(x0, x1), fmaxf(x2v, x3));
#pragma unroll
        for (int d = 1; d < 64; d <<= 1) m = fmaxf(m, __shfl_xor(m, d));
        float e0 = act ? __expf(x0 - m) : 0.f;
        float e1 = act ? __expf(x1 - m) : 0.f;
        float e2 = act ? __expf(x2v - m) : 0.f;
        float e3 = act ? __expf(x3 - m) : 0.f;
        float s = e0 + e1 + e2 + e3;
#pragma unroll
        for (int d = 1; d < 64; d <<= 1) s += __shfl_xor(s, d);
        float inv = 0.8f / s;
        hp0 = act ? fmaf(e0, inv, 0.001f) : 0.f;
        hp1 = act ? fmaf(e1, inv, 0.001f) : 0.f;
        hp2 = act ? fmaf(e2, inv, 0.001f) : 0.f;
        hp3 = act ? fmaf(e3, inv, 0.001f) : 0.f;
    }
    float hc0 = hp0, hc1 = hc0 + hp1, hc2 = hc1 + hp2, hc3 = hc2 + hp3;
    float hrun = hc3, hts = hrun;
#pragma unroll
    for (int d = 1; d < 64; d <<= 1) { float u = __shfl_up(hts, d); if (lane >= d) hts += u; }
    float hexcl = hts - hrun;
    float ch0 = fmaf(sa, hexcl, sb);
    float ch1 = fmaf(sa, hexcl + hc0, sb);
    float ch2 = fmaf(sa, hexcl + hc1, sb);
    float ch3 = fmaf(sa, hexcl + hc2, sb);

    // ---- D (softplus): dd[4l..4l+3] = {dprev, dv0, dv1, dv2} ----
    float dv0, dv1, dv2, dv3;
    {
        float x0 = 0.f, x1 = 0.f, x2v = 0.f, x3 = 0.f;
        if (act) {
            bf16x4 v = *(const bf16x4*)&spr[400 + 4 * lane];
            x0 = (float)v[0]; x1 = (float)v[1]; x2v = (float)v[2]; x3 = (float)v[3];
        }
        auto spls = [](float x) {
            return fmaxf(x, 0.f) + __logf(1.f + __expf(-fabsf(x))) + 0.001f;
        };
        dv0 = spls(x0); dv1 = spls(x1); dv2 = spls(x2v); dv3 = spls(x3);
    }
    if (lane == 49) dv3 = EC;                     // dd[200] = EDGE
    float dprev = __shfl_up(dv3, 1);
    if (lane == 0) dprev = EC;                    // dd[0] = EDGE

    // ---- write param tables (aligned 16B stores) + tails ----
    if (act) {
        *(f32x4*)&cw[4 * lane] = (f32x4){cwl0, cwl1, cwl2, cwl3};
        *(f32x4*)&ch[4 * lane] = (f32x4){ch0, ch1, ch2, ch3};
        *(f32x4*)&dd[4 * lane] = (f32x4){dprev, dv0, dv1, dv2};
    }
    if (lane == 49) {
        cw[200] = 1.0f;                           // cw[:, -1].set(1.0)
        ch[200] = fmaf(sa, hts, sb);              // sa * total + sb
        dd[200] = EC;
    }

    // ---- scatter bin indices (tiny body; exact partition of [0,200)) ----
    if (act) {
        int b0 = rng(cwl0), b1 = rng(cwl1), b2 = rng(cwl2), b3 = rng(cwl3);
        int b4 = (lane == 49) ? 200 : rng(nexcl);
        for (int j = b0; j < b1; ++j) bx[j] = 4 * lane;
        for (int j = b1; j < b2; ++j) bx[j] = 4 * lane + 1;
        for (int j = b2; j < b3; ++j) bx[j] = 4 * lane + 2;
        for (int j = b3; j < b4; ++j) bx[j] = 4 * lane + 3;
    }
    asm volatile("s_waitcnt lgkmcnt(0)" ::: "memory");   // same-wave LDS RAW

    // ---- balanced gather: lane -> outputs j = lane + 50k ----
    if (act) {
        float* orow = out + (size_t)row * 200;
#pragma unroll
        for (int k = 0; k < 4; ++k) {
            int j = lane + 50 * k;
            int b = bx[j];
            float wl = cw[b], wr = cw[b + 1];
            float hl = ch[b], hr = ch[b + 1];
            float d0 = dd[b], d1 = dd[b + 1];
            float tau = ((float)j + 0.5f) * (1.f / 200.f);
            float w = wr - wl, h = hr - hl;
            float invw = 1.f / w;
            float delta = h * invw;
            float th = (tau - wl) * invw;
            float t1 = th * (1.f - th);
            float numer = h * fmaf(delta * th, th, d0 * t1);
            float denom = fmaf(d0 + d1 - 2.f * delta, t1, delta);
            orow[j] = hl + numer / denom;
        }
    }
}

// ---------------------------------------------------------------------------
// Host launcher
// ---------------------------------------------------------------------------
extern "C" void kernel_launch(void* const* d_in, const int* in_sizes, int n_in,
                              void* d_out, int out_size, void* d_ws, size_t ws_size,
                              hipStream_t stream)
{
    const float* inputs = (const float*)d_in[0];
    const float* W1  = (const float*)d_in[1];
    const float* b1  = (const float*)d_in[2];
    const float* g1  = (const float*)d_in[3];
    const float* be1 = (const float*)d_in[4];
    const float* W2  = (const float*)d_in[5];
    const float* b2  = (const float*)d_in[6];
    const float* g2  = (const float*)d_in[7];
    const float* be2 = (const float*)d_in[8];
    const float* WV  = (const float*)d_in[9];
    const float* bV  = (const float*)d_in[10];
    const float* Wa  = (const float*)d_in[11];
    const float* ba  = (const float*)d_in[12];
    const float* Wb  = (const float*)d_in[13];
    const float* bb  = (const float*)d_in[14];
    float* out = (float*)d_out;

    char* ws = (char*)d_ws;
    bf16*  w1b  = (bf16*) (ws + 0);          //   131072
    bf16*  w2b  = (bf16*) (ws + 131072);     //   524288
    bf16*  wcat = (bf16*) (ws + 655360);     //   655360 (640x512)
    float* bcat = (float*)(ws + 1310720);    //     2560 (640 f32)
    float* ab   = (float*)(ws + 1313280);    //   524288 (B x 2)
    bf16*  x    = (bf16*) (ws + 2097152);    // 67108864 (B x 512)
    bf16*  spb  = (bf16*) (ws + 69206016);   // 79167488 (B x 604)
    bf16*  xin  = (bf16*) (ws + 69206016);   // 16777216 (B x 128) — dead before G3 writes spb

    const int preptot = BATCH * 128 / 8 + 512 * 128 + 512 * 512 + NCAT * 512 + NCAT;
    prep_kernel<<<(preptot + 255) / 256, 256, 0, stream>>>(
        W1, W2, WV, bV, Wa, ba, Wb, bb, inputs, w1b, w2b, wcat, bcat, xin);

    fused_mlp<<<BATCH / 64, 512, 0, stream>>>(
        xin, w1b, b1, g1, be1, w2b, b2, g2, be2, x);
    gemm_cat<<<BATCH / 64, 512, 0, stream>>>(x, wcat, bcat, spb, ab);
    spline_kernel<<<BATCH / 4, 256, 0, stream>>>(spb, ab, out);
}

// Round 7
// 266.211 us; speedup vs baseline: 1.6795x; 1.6795x over previous
//
#include <hip/hip_runtime.h>
#include <stdint.h>

typedef __bf16 bf16;
typedef __bf16 bf16x8 __attribute__((ext_vector_type(8)));
typedef __bf16 bf16x4 __attribute__((ext_vector_type(4)));
typedef float  f32x4  __attribute__((ext_vector_type(4)));
typedef uint32_t u32;

#define BATCH    65536
#define NCAT     640      // 599 spline logits + a + b, padded to 640
#define SPSTRIDE 604      // sp row stride in elements

#define MFMA __builtin_amdgcn_mfma_f32_16x16x32_bf16

// async global->LDS, 16B per lane; LDS dest = wave-uniform base + lane*16
__device__ __forceinline__ void async16(const void* g, void* l) {
    __builtin_amdgcn_global_load_lds(
        (const u32 __attribute__((address_space(1)))*)g,
        (u32 __attribute__((address_space(3)))*)l,
        16, 0, 0);
}

// ---------------------------------------------------------------------------
// Kernel 0: weights -> bf16; Wcat[640][512] = [WV; Wa; Wb; 0]; inputs -> bf16
// ---------------------------------------------------------------------------
__global__ __launch_bounds__(256) void prep_kernel(
    const float* W1, const float* W2, const float* WV,
    const float* bV, const float* Wa, const float* ba,
    const float* Wb, const float* bb, const float* inputs,
    bf16* w1b, bf16* w2b, bf16* wcat, float* bcat, bf16* xin)
{
    int idx = blockIdx.x * 256 + threadIdx.x;
    const int n1 = 512 * 128, n2 = 512 * 512, n3 = NCAT * 512;
    const int n5 = BATCH * 128 / 8;                 // 8 floats per item
    if (idx < n5) {                                  // input cast (bulk) first
        const float4* src = (const float4*)(inputs + idx * 8);
        float4 v0 = src[0], v1 = src[1];
        bf16x8 h;
        h[0]=(bf16)v0.x; h[1]=(bf16)v0.y; h[2]=(bf16)v0.z; h[3]=(bf16)v0.w;
        h[4]=(bf16)v1.x; h[5]=(bf16)v1.y; h[6]=(bf16)v1.z; h[7]=(bf16)v1.w;
        *(bf16x8*)&xin[idx * 8] = h;
        return;
    }
    idx -= n5;
    if (idx < n1) { w1b[idx] = (bf16)W1[idx]; return; }
    idx -= n1;
    if (idx < n2) { w2b[idx] = (bf16)W2[idx]; return; }
    idx -= n2;
    if (idx < n3) {
        int n = idx >> 9, k = idx & 511;
        float v = 0.f;
        if (n < 599)       v = WV[n * 512 + k];
        else if (n == 599) v = Wa[k];
        else if (n == 600) v = Wb[k];
        wcat[idx] = (bf16)v;
        return;
    }
    idx -= n3;
    if (idx < NCAT) {
        float v = 0.f;
        if (idx < 599)       v = bV[idx];
        else if (idx == 599) v = ba[0];
        else if (idx == 600) v = bb[0];
        bcat[idx] = v;
    }
}

// ---------------------------------------------------------------------------
// G1/G2: C[128 x 512] = A[128 x K] @ W[512 x K]^T + b -> LN -> ReLU -> bf16
// 16 waves 4Mx4N, wave tile 32x128 (acc[2][8]).  B: dbuf LDS via
// global_load_lds 16B.  A: direct global->VGPR, reg-prefetched 1 step ahead.
// Output staged in LDS (two 64-row halves) -> dense 16B stores.
// ---------------------------------------------------------------------------
template <int KDIM>
__global__ __launch_bounds__(1024, 4) void gemm_ln(
    const bf16* __restrict__ A, const bf16* __restrict__ W,
    const float* __restrict__ bias, const float* __restrict__ gamma,
    const float* __restrict__ beta, bf16* out)
{
    __shared__ __align__(16) char smem[65536];      // B dbuf 2x32K; stage-out
    __shared__ float Psum[128][4], Psq[128][4];

    const int t = threadIdx.x;
    const int lane = t & 63, wid = t >> 6;
    const int wm = wid >> 2, wn = wid & 3;
    const int l16 = lane & 15, g16 = lane >> 4;
    const long row0 = (long)blockIdx.x * 128;
    constexpr int NT = KDIM / 32;

    const bf16* arow0 = A + (row0 + wm * 32 + l16) * (long)KDIM + g16 * 8;
    const bf16* arow1 = arow0 + 16 * KDIM;

    f32x4 acc[2][8];
#pragma unroll
    for (int a = 0; a < 2; ++a)
#pragma unroll
        for (int b = 0; b < 8; ++b) acc[a][b] = (f32x4){0.f, 0.f, 0.f, 0.f};

    auto stageB = [&](int kt, int bi) {     // 32 calls of 1KB: 2 per wave
#pragma unroll
        for (int c = 0; c < 2; ++c) {
            int call = c * 16 + wid;
            int row = call * 16 + (lane >> 2);
            const bf16* src = W + (long)row * KDIM + kt * 32 + (lane & 3) * 8;
            async16(src, smem + bi * 32768 + call * 1024);
        }
    };

    stageB(0, 0);
    bf16x8 af0 = *(const bf16x8*)(arow0);
    bf16x8 af1 = *(const bf16x8*)(arow1);
    __syncthreads();

    for (int kt = 0; kt < NT; ++kt) {
        const int bi = kt & 1;
        bf16x8 a0 = af0, a1 = af1;
        if (kt + 1 < NT) {
            stageB(kt + 1, bi ^ 1);
            af0 = *(const bf16x8*)(arow0 + (kt + 1) * 32);
            af1 = *(const bf16x8*)(arow1 + (kt + 1) * 32);
        }
        const bf16* Bb = (const bf16*)(smem + bi * 32768);
#pragma unroll
        for (int fn = 0; fn < 8; ++fn) {
            bf16x8 bv = *(const bf16x8*)(Bb + (wn * 128 + fn * 16 + l16) * 32 + g16 * 8);
            acc[0][fn] = MFMA(a0, bv, acc[0][fn], 0, 0, 0);
            acc[1][fn] = MFMA(a1, bv, acc[1][fn], 0, 0, 0);
        }
        __syncthreads();
    }

    // ---- epilogue: +bias, LN over 512, ReLU -> two-half staged writeout ----
    float gv[8], bev[8];
#pragma unroll
    for (int fn = 0; fn < 8; ++fn) {
        int col = wn * 128 + fn * 16 + l16;
        float bv = bias[col];
        gv[fn] = gamma[col]; bev[fn] = beta[col];
#pragma unroll
        for (int fm = 0; fm < 2; ++fm)
#pragma unroll
            for (int i = 0; i < 4; ++i) acc[fm][fn][i] += bv;
    }
#pragma unroll
    for (int fm = 0; fm < 2; ++fm)
#pragma unroll
        for (int i = 0; i < 4; ++i) {
            float s = 0.f, q = 0.f;
#pragma unroll
            for (int fn = 0; fn < 8; ++fn) { float v = acc[fm][fn][i]; s += v; q += v * v; }
#pragma unroll
            for (int m = 1; m < 16; m <<= 1) { s += __shfl_xor(s, m); q += __shfl_xor(q, m); }
            if (l16 == 0) {
                int lr = wm * 32 + fm * 16 + g16 * 4 + i;
                Psum[lr][wn] = s; Psq[lr][wn] = q;
            }
        }
    __syncthreads();
    float mmean[2][4], mrstd[2][4];
#pragma unroll
    for (int fm = 0; fm < 2; ++fm)
#pragma unroll
        for (int i = 0; i < 4; ++i) {
            int lr = wm * 32 + fm * 16 + g16 * 4 + i;
            float s = Psum[lr][0] + Psum[lr][1] + Psum[lr][2] + Psum[lr][3];
            float q = Psq[lr][0] + Psq[lr][1] + Psq[lr][2] + Psq[lr][3];
            float mean = s * (1.f / 512.f);
            float var  = q * (1.f / 512.f) - mean * mean;
            mmean[fm][i] = mean;
            mrstd[fm][i] = rsqrtf(var + 1e-5f);
        }
    bf16* stg = (bf16*)smem;
#pragma unroll
    for (int h = 0; h < 2; ++h) {
        __syncthreads();
#pragma unroll
        for (int fm = 0; fm < 2; ++fm)
#pragma unroll
            for (int i = 0; i < 4; ++i) {
                int lr = wm * 32 + fm * 16 + g16 * 4 + i;
                if ((lr >> 6) != h) continue;
#pragma unroll
                for (int fn = 0; fn < 8; ++fn) {
                    int col = wn * 128 + fn * 16 + l16;
                    float o = (acc[fm][fn][i] - mmean[fm][i]) * mrstd[fm][i] * gv[fn] + bev[fn];
                    stg[(lr & 63) * 512 + col] = (bf16)fmaxf(o, 0.f);
                }
            }
        __syncthreads();
#pragma unroll
        for (int it = 0; it < 4; ++it) {          // 64 rows x 1KB dense
            int idx = it * 1024 + t;
            *(bf16x8*)&out[(row0 + h * 64 + (idx >> 6)) * 512 + (idx & 63) * 8] =
                *(const bf16x8*)&stg[idx * 8];
        }
    }
}

// ---------------------------------------------------------------------------
// G3: sp[128 x 640] = X2[128 x 512] @ Wcat^T + bcat.
// 16 waves 4Mx4N, wave tile 32x160 (acc[2][10]). B dbuf LDS, A direct+prefetch.
// Output staged in LDS (two 64-row halves) -> dense 8B writeout; ab f32 direct.
// ---------------------------------------------------------------------------
__global__ __launch_bounds__(1024, 4) void gemm_cat(
    const bf16* __restrict__ A, const bf16* __restrict__ W,
    const float* __restrict__ bcat, bf16* __restrict__ sp, float* __restrict__ ab)
{
    __shared__ __align__(16) char smem[81920];      // B dbuf 2x40K; stage-out

    const int t = threadIdx.x;
    const int lane = t & 63, wid = t >> 6;
    const int wm = wid >> 2, wn = wid & 3;
    const int l16 = lane & 15, g16 = lane >> 4;
    const long row0 = (long)blockIdx.x * 128;

    const bf16* arow0 = A + (row0 + wm * 32 + l16) * 512 + g16 * 8;
    const bf16* arow1 = arow0 + 16 * 512;

    f32x4 acc[2][10];
#pragma unroll
    for (int a = 0; a < 2; ++a)
#pragma unroll
        for (int b = 0; b < 10; ++b) acc[a][b] = (f32x4){0.f, 0.f, 0.f, 0.f};

    auto stageB = [&](int kt, int bi) {     // 40 calls of 1KB
#pragma unroll
        for (int c = 0; c < 3; ++c) {
            int call = c * 16 + wid;
            if (call < 40) {
                int row = call * 16 + (lane >> 2);
                const bf16* src = W + (long)row * 512 + kt * 32 + (lane & 3) * 8;
                async16(src, smem + bi * 40960 + call * 1024);
            }
        }
    };

    stageB(0, 0);
    bf16x8 af0 = *(const bf16x8*)(arow0);
    bf16x8 af1 = *(const bf16x8*)(arow1);
    __syncthreads();

    for (int kt = 0; kt < 16; ++kt) {
        const int bi = kt & 1;
        bf16x8 a0 = af0, a1 = af1;
        if (kt < 15) {
            stageB(kt + 1, bi ^ 1);
            af0 = *(const bf16x8*)(arow0 + (kt + 1) * 32);
            af1 = *(const bf16x8*)(arow1 + (kt + 1) * 32);
        }
        const bf16* Bb = (const bf16*)(smem + bi * 40960);
#pragma unroll
        for (int fn = 0; fn < 10; ++fn) {
            bf16x8 bv = *(const bf16x8*)(Bb + (wn * 160 + fn * 16 + l16) * 32 + g16 * 8);
            acc[0][fn] = MFMA(a0, bv, acc[0][fn], 0, 0, 0);
            acc[1][fn] = MFMA(a1, bv, acc[1][fn], 0, 0, 0);
        }
        __syncthreads();
    }

    // ---- +bcat; ab f32 direct; two-half staged dense writeout ----
    float bv[10];
#pragma unroll
    for (int fn = 0; fn < 10; ++fn) bv[fn] = bcat[wn * 160 + fn * 16 + l16];

#pragma unroll
    for (int fn = 0; fn < 10; ++fn) {
        int col = wn * 160 + fn * 16 + l16;
        if (col == 599 || col == 600) {
#pragma unroll
            for (int fm = 0; fm < 2; ++fm)
#pragma unroll
                for (int i = 0; i < 4; ++i) {
                    int lr = wm * 32 + fm * 16 + g16 * 4 + i;
                    ab[(row0 + lr) * 2 + (col - 599)] = acc[fm][fn][i] + bv[fn];
                }
        }
    }

    bf16* stg = (bf16*)smem;
#pragma unroll
    for (int h = 0; h < 2; ++h) {
        __syncthreads();
#pragma unroll
        for (int fn = 0; fn < 10; ++fn) {
            int col = wn * 160 + fn * 16 + l16;
            if (col >= SPSTRIDE) continue;
#pragma unroll
            for (int fm = 0; fm < 2; ++fm)
#pragma unroll
                for (int i = 0; i < 4; ++i) {
                    int lr = wm * 32 + fm * 16 + g16 * 4 + i;
                    if ((lr >> 6) != h) continue;
                    stg[(lr & 63) * SPSTRIDE + col] = (bf16)(acc[fm][fn][i] + bv[fn]);
                }
        }
        __syncthreads();
#pragma unroll
        for (int it = 0; it < 10; ++it) {         // 64 rows x 151 8B-chunks
            int c = it * 1024 + t;
            if (c < 64 * 151) {
                int r = c / 151, k = c - r * 151;
                *(uint64_t*)&sp[(row0 + h * 64 + r) * SPSTRIDE + k * 4] =
                    *(const uint64_t*)&stg[r * SPSTRIDE + k * 4];
            }
        }
    }
}

// ---------------------------------------------------------------------------
// Spline v3: register scan -> LDS param tables -> binidx scatter ->
// balanced gather (lane computes exactly 4 outputs j = lane + 50k).
// ---------------------------------------------------------------------------
__global__ __launch_bounds__(256) void spline_kernel(
    const bf16* __restrict__ sp, const float* __restrict__ ab, float* __restrict__ out)
{
    __shared__ float S[4][816];     // per wave: cw@0, ch@204, dd@408, binidx@612
    const int t = threadIdx.x;
    const int lane = t & 63, wid = t >> 6;
    const long row = (long)blockIdx.x * 4 + wid;
    const bf16* spr = sp + row * SPSTRIDE;
    const bool act = lane < 50;
    const float EC = 0.53974247f;                 // log(exp(0.999)-1)
    float* cw = &S[wid][0];
    float* ch = &S[wid][204];
    float* dd = &S[wid][408];
    int*   bx = (int*)&S[wid][612];

    const float sa = __expf(ab[row * 2 + 0]);
    const float sb = ab[row * 2 + 1];

    auto rng = [](float x) -> int {               // first j with tau_j >= x
        int v = (int)ceilf(fmaf(200.f, x, -0.5f));
        return v < 0 ? 0 : (v > 200 ? 200 : v);
    };

    // ---- W logits -> widths -> cw[4l..4l+3] in regs ----
    float p0, p1, p2, p3;
    {
        float x0, x1, x2v, x3;
        if (act) {
            bf16x4 v = *(const bf16x4*)&spr[4 * lane];
            x0 = (float)v[0]; x1 = (float)v[1]; x2v = (float)v[2]; x3 = (float)v[3];
        } else { x0 = x1 = x2v = x3 = -1e30f; }
        float m = fmaxf(fmaxf(x0, x1), fmaxf(x2v, x3));
#pragma unroll
        for (int d = 1; d < 64; d <<= 1) m = fmaxf(m, __shfl_xor(m, d));
        float e0 = act ? __expf(x0 - m) : 0.f;
        float e1 = act ? __expf(x1 - m) : 0.f;
        float e2 = act ? __expf(x2v - m) : 0.f;
        float e3 = act ? __expf(x3 - m) : 0.f;
        float s = e0 + e1 + e2 + e3;
#pragma unroll
        for (int d = 1; d < 64; d <<= 1) s += __shfl_xor(s, d);
        float inv = 0.8f / s;
        p0 = act ? fmaf(e0, inv, 0.001f) : 0.f;
        p1 = act ? fmaf(e1, inv, 0.001f) : 0.f;
        p2 = act ? fmaf(e2, inv, 0.001f) : 0.f;
        p3 = act ? fmaf(e3, inv, 0.001f) : 0.f;
    }
    float c0 = p0, c1 = c0 + p1, c2 = c1 + p2, c3 = c2 + p3;
    float run = c3, ts = run;
#pragma unroll
    for (int d = 1; d < 64; d <<= 1) { float u = __shfl_up(ts, d); if (lane >= d) ts += u; }
    float excl  = ts - run;
    float nexcl = __shfl_down(excl, 1);
    float cwl0 = excl, cwl1 = excl + c0, cwl2 = excl + c1, cwl3 = excl + c2;

    // ---- H logits -> heights -> ch[4l..4l+3] ----
    float hp0, hp1, hp2, hp3;
    {
        float x0, x1, x2v, x3;
        if (act) {
            bf16x4 v = *(const bf16x4*)&spr[200 + 4 * lane];
            x0 = (float)v[0]; x1 = (float)v[1]; x2v = (float)v[2]; x3 = (float)v[3];
        } else { x0 = x1 = x2v = x3 = -1e30f; }
        float m = fmaxf(fmaxf(x0, x1), fmaxf(x2v, x3));
#pragma unroll
        for (int d = 1; d < 64; d <<= 1) m = fmaxf(m, __shfl_xor(m, d));
        float e0 = act ? __expf(x0 - m) : 0.f;
        float e1 = act ? __expf(x1 - m) : 0.f;
        float e2 = act ? __expf(x2v - m) : 0.f;
        float e3 = act ? __expf(x3 - m) : 0.f;
        float s = e0 + e1 + e2 + e3;
#pragma unroll
        for (int d = 1; d < 64; d <<= 1) s += __shfl_xor(s, d);
        float inv = 0.8f / s;
        hp0 = act ? fmaf(e0, inv, 0.001f) : 0.f;
        hp1 = act ? fmaf(e1, inv, 0.001f) : 0.f;
        hp2 = act ? fmaf(e2, inv, 0.001f) : 0.f;
        hp3 = act ? fmaf(e3, inv, 0.001f) : 0.f;
    }
    float hc0 = hp0, hc1 = hc0 + hp1, hc2 = hc1 + hp2, hc3 = hc2 + hp3;
    float hrun = hc3, hts = hrun;
#pragma unroll
    for (int d = 1; d < 64; d <<= 1) { float u = __shfl_up(hts, d); if (lane >= d) hts += u; }
    float hexcl = hts - hrun;
    float ch0 = fmaf(sa, hexcl, sb);
    float ch1 = fmaf(sa, hexcl + hc0, sb);
    float ch2 = fmaf(sa, hexcl + hc1, sb);
    float ch3 = fmaf(sa, hexcl + hc2, sb);

    // ---- D (softplus): dd[4l..4l+3] = {dprev, dv0, dv1, dv2} ----
    float dv0, dv1, dv2, dv3;
    {
        float x0 = 0.f, x1 = 0.f, x2v = 0.f, x3 = 0.f;
        if (act) {
            bf16x4 v = *(const bf16x4*)&spr[400 + 4 * lane];
            x0 = (float)v[0]; x1 = (float)v[1]; x2v = (float)v[2]; x3 = (float)v[3];
        }
        auto spls = [](float x) {
            return fmaxf(x, 0.f) + __logf(1.f + __expf(-fabsf(x))) + 0.001f;
        };
        dv0 = spls(x0); dv1 = spls(x1); dv2 = spls(x2v); dv3 = spls(x3);
    }
    if (lane == 49) dv3 = EC;                     // dd[200] = EDGE
    float dprev = __shfl_up(dv3, 1);
    if (lane == 0) dprev = EC;                    // dd[0] = EDGE

    // ---- write param tables (aligned 16B stores) + tails ----
    if (act) {
        *(f32x4*)&cw[4 * lane] = (f32x4){cwl0, cwl1, cwl2, cwl3};
        *(f32x4*)&ch[4 * lane] = (f32x4){ch0, ch1, ch2, ch3};
        *(f32x4*)&dd[4 * lane] = (f32x4){dprev, dv0, dv1, dv2};
    }
    if (lane == 49) {
        cw[200] = 1.0f;                           // cw[:, -1].set(1.0)
        ch[200] = fmaf(sa, hts, sb);              // sa * total + sb
        dd[200] = EC;
    }

    // ---- scatter bin indices (tiny body; exact partition of [0,200)) ----
    if (act) {
        int b0 = rng(cwl0), b1 = rng(cwl1), b2 = rng(cwl2), b3 = rng(cwl3);
        int b4 = (lane == 49) ? 200 : rng(nexcl);
        for (int j = b0; j < b1; ++j) bx[j] = 4 * lane;
        for (int j = b1; j < b2; ++j) bx[j] = 4 * lane + 1;
        for (int j = b2; j < b3; ++j) bx[j] = 4 * lane + 2;
        for (int j = b3; j < b4; ++j) bx[j] = 4 * lane + 3;
    }
    asm volatile("s_waitcnt lgkmcnt(0)" ::: "memory");   // same-wave LDS RAW

    // ---- balanced gather: lane -> outputs j = lane + 50k ----
    if (act) {
        float* orow = out + (size_t)row * 200;
#pragma unroll
        for (int k = 0; k < 4; ++k) {
            int j = lane + 50 * k;
            int b = bx[j];
            float wl = cw[b], wr = cw[b + 1];
            float hl = ch[b], hr = ch[b + 1];
            float d0 = dd[b], d1 = dd[b + 1];
            float tau = ((float)j + 0.5f) * (1.f / 200.f);
            float w = wr - wl, h = hr - hl;
            float invw = 1.f / w;
            float delta = h * invw;
            float th = (tau - wl) * invw;
            float t1 = th * (1.f - th);
            float numer = h * fmaf(delta * th, th, d0 * t1);
            float denom = fmaf(d0 + d1 - 2.f * delta, t1, delta);
            orow[j] = hl + numer / denom;
        }
    }
}

// ---------------------------------------------------------------------------
// Host launcher
// ---------------------------------------------------------------------------
extern "C" void kernel_launch(void* const* d_in, const int* in_sizes, int n_in,
                              void* d_out, int out_size, void* d_ws, size_t ws_size,
                              hipStream_t stream)
{
    const float* inputs = (const float*)d_in[0];
    const float* W1  = (const float*)d_in[1];
    const float* b1  = (const float*)d_in[2];
    const float* g1  = (const float*)d_in[3];
    const float* be1 = (const float*)d_in[4];
    const float* W2  = (const float*)d_in[5];
    const float* b2  = (const float*)d_in[6];
    const float* g2  = (const float*)d_in[7];
    const float* be2 = (const float*)d_in[8];
    const float* WV  = (const float*)d_in[9];
    const float* bV  = (const float*)d_in[10];
    const float* Wa  = (const float*)d_in[11];
    const float* ba  = (const float*)d_in[12];
    const float* Wb  = (const float*)d_in[13];
    const float* bb  = (const float*)d_in[14];
    float* out = (float*)d_out;

    char* ws = (char*)d_ws;
    bf16*  w1b  = (bf16*) (ws + 0);          //   131072
    bf16*  w2b  = (bf16*) (ws + 131072);     //   524288
    bf16*  wcat = (bf16*) (ws + 655360);     //   655360 (640x512)
    float* bcat = (float*)(ws + 1310720);    //     2560 (640 f32)
    float* ab   = (float*)(ws + 1313280);    //   524288 (B x 2)
    bf16*  x    = (bf16*) (ws + 2097152);    // 67108864 (B x 512)
    bf16*  spb  = (bf16*) (ws + 69206016);   // 79167488 (B x 604)
    bf16*  xin  = (bf16*) (ws + 69206016);   // 16777216 (B x 128) — dead before G3 writes spb

    const int preptot = BATCH * 128 / 8 + 512 * 128 + 512 * 512 + NCAT * 512 + NCAT;
    prep_kernel<<<(preptot + 255) / 256, 256, 0, stream>>>(
        W1, W2, WV, bV, Wa, ba, Wb, bb, inputs, w1b, w2b, wcat, bcat, xin);

    gemm_ln<128><<<BATCH / 128, 1024, 0, stream>>>(xin, w1b, b1, g1, be1, x);
    gemm_ln<512><<<BATCH / 128, 1024, 0, stream>>>(x,   w2b, b2, g2, be2, x);
    gemm_cat<<<BATCH / 128, 1024, 0, stream>>>(x, wcat, bcat, spb, ab);
    spline_kernel<<<BATCH / 4, 256, 0, stream>>>(spb, ab, out);
}

// Round 8
// 263.946 us; speedup vs baseline: 1.6939x; 1.0086x over previous
//
#include <hip/hip_runtime.h>
#include <stdint.h>

typedef __bf16 bf16;
typedef __bf16 bf16x8 __attribute__((ext_vector_type(8)));
typedef __bf16 bf16x4 __attribute__((ext_vector_type(4)));
typedef float  f32x4  __attribute__((ext_vector_type(4)));
typedef uint32_t u32;

#define BATCH 65536
#define NCAT  640      // 599 spline logits + a + b, padded to 640

#define MFMA __builtin_amdgcn_mfma_f32_16x16x32_bf16
#define FENCE() asm volatile("" ::: "memory")

// async global->LDS, 16B per lane; LDS dest = wave-uniform base + lane*16
__device__ __forceinline__ void async16(const void* g, void* l) {
    __builtin_amdgcn_global_load_lds(
        (const u32 __attribute__((address_space(1)))*)g,
        (u32 __attribute__((address_space(3)))*)l,
        16, 0, 0);
}

// ---------------------------------------------------------------------------
// Kernel 0: weights -> bf16; Wcat[640][512] = [WV; Wa; Wb; 0]; inputs -> bf16
// ---------------------------------------------------------------------------
__global__ __launch_bounds__(256) void prep_kernel(
    const float* W1, const float* W2, const float* WV,
    const float* bV, const float* Wa, const float* ba,
    const float* Wb, const float* bb, const float* inputs,
    bf16* w1b, bf16* w2b, bf16* wcat, float* bcat, bf16* xin)
{
    int idx = blockIdx.x * 256 + threadIdx.x;
    const int n1 = 512 * 128, n2 = 512 * 512, n3 = NCAT * 512;
    const int n5 = BATCH * 128 / 8;                 // 8 floats per item
    if (idx < n5) {                                  // input cast (bulk) first
        const float4* src = (const float4*)(inputs + idx * 8);
        float4 v0 = src[0], v1 = src[1];
        bf16x8 h;
        h[0]=(bf16)v0.x; h[1]=(bf16)v0.y; h[2]=(bf16)v0.z; h[3]=(bf16)v0.w;
        h[4]=(bf16)v1.x; h[5]=(bf16)v1.y; h[6]=(bf16)v1.z; h[7]=(bf16)v1.w;
        *(bf16x8*)&xin[idx * 8] = h;
        return;
    }
    idx -= n5;
    if (idx < n1) { w1b[idx] = (bf16)W1[idx]; return; }
    idx -= n1;
    if (idx < n2) { w2b[idx] = (bf16)W2[idx]; return; }
    idx -= n2;
    if (idx < n3) {
        int n = idx >> 9, k = idx & 511;
        float v = 0.f;
        if (n < 599)       v = WV[n * 512 + k];
        else if (n == 599) v = Wa[k];
        else if (n == 600) v = Wb[k];
        wcat[idx] = (bf16)v;
        return;
    }
    idx -= n3;
    if (idx < NCAT) {
        float v = 0.f;
        if (idx < 599)       v = bV[idx];
        else if (idx == 599) v = ba[0];
        else if (idx == 600) v = bb[0];
        bcat[idx] = v;
    }
}

// ---------------------------------------------------------------------------
// G1/G2: C[128 x 512] = A[128 x K] @ W[512 x K]^T + b -> LN -> ReLU -> bf16
// 16 waves 4Mx4N, wave tile 32x128 (acc[2][8]). B: dbuf LDS via
// global_load_lds. A: direct global->VGPR, prefetched 1 step ahead.
// K-loop uses COUNTED vmcnt + raw s_barrier: stage loads drain exactly,
// A-prefetch (2 newest loads) stays in flight across the barrier.
// Output staged in LDS (two 64-row halves) -> dense 16B stores.
// ---------------------------------------------------------------------------
template <int KDIM>
__global__ __launch_bounds__(1024, 4) void gemm_ln(
    const bf16* __restrict__ A, const bf16* __restrict__ W,
    const float* __restrict__ bias, const float* __restrict__ gamma,
    const float* __restrict__ beta, bf16* out)
{
    __shared__ __align__(16) char smem[65536];      // B dbuf 2x32K; stage-out
    __shared__ float Psum[128][4], Psq[128][4];

    const int t = threadIdx.x;
    const int lane = t & 63, wid = t >> 6;
    const int wm = wid >> 2, wn = wid & 3;
    const int l16 = lane & 15, g16 = lane >> 4;
    const long row0 = (long)blockIdx.x * 128;
    constexpr int NT = KDIM / 32;

    const bf16* arow0 = A + (row0 + wm * 32 + l16) * (long)KDIM + g16 * 8;
    const bf16* arow1 = arow0 + 16 * KDIM;

    f32x4 acc[2][8];
#pragma unroll
    for (int a = 0; a < 2; ++a)
#pragma unroll
        for (int b = 0; b < 8; ++b) acc[a][b] = (f32x4){0.f, 0.f, 0.f, 0.f};

    auto stageB = [&](int kt, int bi) {     // 32 calls of 1KB: 2 per wave
#pragma unroll
        for (int c = 0; c < 2; ++c) {
            int call = c * 16 + wid;
            int row = call * 16 + (lane >> 2);
            const bf16* src = W + (long)row * KDIM + kt * 32 + (lane & 3) * 8;
            async16(src, smem + bi * 32768 + call * 1024);
        }
    };

    stageB(0, 0);
    FENCE();
    bf16x8 af0 = *(const bf16x8*)(arow0);
    bf16x8 af1 = *(const bf16x8*)(arow1);
    asm volatile("s_waitcnt vmcnt(2)\n\ts_barrier" ::: "memory");

    for (int kt = 0; kt < NT; ++kt) {
        const int bi = kt & 1;
        bf16x8 a0 = af0, a1 = af1;
        if (kt + 1 < NT) {
            stageB(kt + 1, bi ^ 1);
            FENCE();
            af0 = *(const bf16x8*)(arow0 + (kt + 1) * 32);
            af1 = *(const bf16x8*)(arow1 + (kt + 1) * 32);
        }
        const bf16* Bb = (const bf16*)(smem + bi * 32768);
#pragma unroll
        for (int fn = 0; fn < 8; ++fn) {
            bf16x8 bv = *(const bf16x8*)(Bb + (wn * 128 + fn * 16 + l16) * 32 + g16 * 8);
            acc[0][fn] = MFMA(a0, bv, acc[0][fn], 0, 0, 0);
            acc[1][fn] = MFMA(a1, bv, acc[1][fn], 0, 0, 0);
        }
        if (kt + 1 < NT)
            asm volatile("s_waitcnt vmcnt(2)\n\ts_barrier" ::: "memory");
    }

    // ---- epilogue: +bias, LN over 512, ReLU -> two-half staged writeout ----
    float gv[8], bev[8];
#pragma unroll
    for (int fn = 0; fn < 8; ++fn) {
        int col = wn * 128 + fn * 16 + l16;
        float bv = bias[col];
        gv[fn] = gamma[col]; bev[fn] = beta[col];
#pragma unroll
        for (int fm = 0; fm < 2; ++fm)
#pragma unroll
            for (int i = 0; i < 4; ++i) acc[fm][fn][i] += bv;
    }
#pragma unroll
    for (int fm = 0; fm < 2; ++fm)
#pragma unroll
        for (int i = 0; i < 4; ++i) {
            float s = 0.f, q = 0.f;
#pragma unroll
            for (int fn = 0; fn < 8; ++fn) { float v = acc[fm][fn][i]; s += v; q += v * v; }
#pragma unroll
            for (int m = 1; m < 16; m <<= 1) { s += __shfl_xor(s, m); q += __shfl_xor(q, m); }
            if (l16 == 0) {
                int lr = wm * 32 + fm * 16 + g16 * 4 + i;
                Psum[lr][wn] = s; Psq[lr][wn] = q;
            }
        }
    __syncthreads();
    float mmean[2][4], mrstd[2][4];
#pragma unroll
    for (int fm = 0; fm < 2; ++fm)
#pragma unroll
        for (int i = 0; i < 4; ++i) {
            int lr = wm * 32 + fm * 16 + g16 * 4 + i;
            float s = Psum[lr][0] + Psum[lr][1] + Psum[lr][2] + Psum[lr][3];
            float q = Psq[lr][0] + Psq[lr][1] + Psq[lr][2] + Psq[lr][3];
            float mean = s * (1.f / 512.f);
            float var  = q * (1.f / 512.f) - mean * mean;
            mmean[fm][i] = mean;
            mrstd[fm][i] = rsqrtf(var + 1e-5f);
        }
    bf16* stg = (bf16*)smem;
#pragma unroll
    for (int h = 0; h < 2; ++h) {
        __syncthreads();
#pragma unroll
        for (int fm = 0; fm < 2; ++fm)
#pragma unroll
            for (int i = 0; i < 4; ++i) {
                int lr = wm * 32 + fm * 16 + g16 * 4 + i;
                if ((lr >> 6) != h) continue;
#pragma unroll
                for (int fn = 0; fn < 8; ++fn) {
                    int col = wn * 128 + fn * 16 + l16;
                    float o = (acc[fm][fn][i] - mmean[fm][i]) * mrstd[fm][i] * gv[fn] + bev[fn];
                    stg[(lr & 63) * 512 + col] = (bf16)fmaxf(o, 0.f);
                }
            }
        __syncthreads();
#pragma unroll
        for (int it = 0; it < 4; ++it) {          // 64 rows x 1KB dense
            int idx = it * 1024 + t;
            *(bf16x8*)&out[(row0 + h * 64 + (idx >> 6)) * 512 + (idx & 63) * 8] =
                *(const bf16x8*)&stg[idx * 8];
        }
    }
}

// ---------------------------------------------------------------------------
// Balanced per-row spline (wave-wide): register scan -> per-wave LDS tables
// -> binidx scatter -> balanced gather (lane -> outputs j = lane + 50k).
// ---------------------------------------------------------------------------
__device__ __forceinline__ void spline_row(
    const bf16* spr, float* tab, float a_in, float sb, float* orow, int lane)
{
    const bool act = lane < 50;
    const float EC = 0.53974247f;                 // log(exp(0.999)-1)
    float* cw = tab;
    float* ch = tab + 204;
    float* dd = tab + 408;
    int*   bx = (int*)(tab + 612);
    const float sa = __expf(a_in);

    auto rng = [](float x) -> int {               // first j with tau_j >= x
        int v = (int)ceilf(fmaf(200.f, x, -0.5f));
        return v < 0 ? 0 : (v > 200 ? 200 : v);
    };

    // ---- W logits -> widths -> cw[4l..4l+3] in regs ----
    float p0, p1, p2, p3;
    {
        float x0, x1, x2v, x3;
        if (act) {
            bf16x4 v = *(const bf16x4*)&spr[4 * lane];
            x0 = (float)v[0]; x1 = (float)v[1]; x2v = (float)v[2]; x3 = (float)v[3];
        } else { x0 = x1 = x2v = x3 = -1e30f; }
        float m = fmaxf(fmaxf(x0, x1), fmaxf(x2v, x3));
#pragma unroll
        for (int d = 1; d < 64; d <<= 1) m = fmaxf(m, __shfl_xor(m, d));
        float e0 = act ? __expf(x0 - m) : 0.f;
        float e1 = act ? __expf(x1 - m) : 0.f;
        float e2 = act ? __expf(x2v - m) : 0.f;
        float e3 = act ? __expf(x3 - m) : 0.f;
        float s = e0 + e1 + e2 + e3;
#pragma unroll
        for (int d = 1; d < 64; d <<= 1) s += __shfl_xor(s, d);
        float inv = 0.8f / s;
        p0 = act ? fmaf(e0, inv, 0.001f) : 0.f;
        p1 = act ? fmaf(e1, inv, 0.001f) : 0.f;
        p2 = act ? fmaf(e2, inv, 0.001f) : 0.f;
        p3 = act ? fmaf(e3, inv, 0.001f) : 0.f;
    }
    float c0 = p0, c1 = c0 + p1, c2 = c1 + p2, c3 = c2 + p3;
    float run = c3, ts = run;
#pragma unroll
    for (int d = 1; d < 64; d <<= 1) { float u = __shfl_up(ts, d); if (lane >= d) ts += u; }
    float excl  = ts - run;
    float nexcl = __shfl_down(excl, 1);
    float cwl0 = excl, cwl1 = excl + c0, cwl2 = excl + c1, cwl3 = excl + c2;

    // ---- H logits -> heights -> ch[4l..4l+3] ----
    float hp0, hp1, hp2, hp3;
    {
        float x0, x1, x2v, x3;
        if (act) {
            bf16x4 v = *(const bf16x4*)&spr[200 + 4 * lane];
            x0 = (float)v[0]; x1 = (float)v[1]; x2v = (float)v[2]; x3 = (float)v[3];
        } else { x0 = x1 = x2v = x3 = -1e30f; }
        float m = fmaxf(fmaxf(x0, x1), fmaxf(x2v, x3));
#pragma unroll
        for (int d = 1; d < 64; d <<= 1) m = fmaxf(m, __shfl_xor(m, d));
        float e0 = act ? __expf(x0 - m) : 0.f;
        float e1 = act ? __expf(x1 - m) : 0.f;
        float e2 = act ? __expf(x2v - m) : 0.f;
        float e3 = act ? __expf(x3 - m) : 0.f;
        float s = e0 + e1 + e2 + e3;
#pragma unroll
        for (int d = 1; d < 64; d <<= 1) s += __shfl_xor(s, d);
        float inv = 0.8f / s;
        hp0 = act ? fmaf(e0, inv, 0.001f) : 0.f;
        hp1 = act ? fmaf(e1, inv, 0.001f) : 0.f;
        hp2 = act ? fmaf(e2, inv, 0.001f) : 0.f;
        hp3 = act ? fmaf(e3, inv, 0.001f) : 0.f;
    }
    float hc0 = hp0, hc1 = hc0 + hp1, hc2 = hc1 + hp2, hc3 = hc2 + hp3;
    float hrun = hc3, hts = hrun;
#pragma unroll
    for (int d = 1; d < 64; d <<= 1) { float u = __shfl_up(hts, d); if (lane >= d) hts += u; }
    float hexcl = hts - hrun;
    float ch0 = fmaf(sa, hexcl, sb);
    float ch1 = fmaf(sa, hexcl + hc0, sb);
    float ch2 = fmaf(sa, hexcl + hc1, sb);
    float ch3 = fmaf(sa, hexcl + hc2, sb);

    // ---- D (softplus): dd[4l..4l+3] = {dprev, dv0, dv1, dv2} ----
    float dv0, dv1, dv2, dv3;
    {
        float x0 = 0.f, x1 = 0.f, x2v = 0.f, x3 = 0.f;
        if (act) {
            bf16x4 v = *(const bf16x4*)&spr[400 + 4 * lane];
            x0 = (float)v[0]; x1 = (float)v[1]; x2v = (float)v[2]; x3 = (float)v[3];
        }
        auto spls = [](float x) {
            return fmaxf(x, 0.f) + __logf(1.f + __expf(-fabsf(x))) + 0.001f;
        };
        dv0 = spls(x0); dv1 = spls(x1); dv2 = spls(x2v); dv3 = spls(x3);
    }
    if (lane == 49) dv3 = EC;                     // dd[200] = EDGE
    float dprev = __shfl_up(dv3, 1);
    if (lane == 0) dprev = EC;                    // dd[0] = EDGE

    // ---- write param tables (aligned 16B stores) + tails ----
    if (act) {
        *(f32x4*)&cw[4 * lane] = (f32x4){cwl0, cwl1, cwl2, cwl3};
        *(f32x4*)&ch[4 * lane] = (f32x4){ch0, ch1, ch2, ch3};
        *(f32x4*)&dd[4 * lane] = (f32x4){dprev, dv0, dv1, dv2};
    }
    if (lane == 49) {
        cw[200] = 1.0f;                           // cw[:, -1].set(1.0)
        ch[200] = fmaf(sa, hts, sb);              // sa * total + sb
        dd[200] = EC;
    }

    // ---- scatter bin indices (tiny body; exact partition of [0,200)) ----
    if (act) {
        int b0 = rng(cwl0), b1 = rng(cwl1), b2 = rng(cwl2), b3 = rng(cwl3);
        int b4 = (lane == 49) ? 200 : rng(nexcl);
        for (int j = b0; j < b1; ++j) bx[j] = 4 * lane;
        for (int j = b1; j < b2; ++j) bx[j] = 4 * lane + 1;
        for (int j = b2; j < b3; ++j) bx[j] = 4 * lane + 2;
        for (int j = b3; j < b4; ++j) bx[j] = 4 * lane + 3;
    }
    asm volatile("s_waitcnt lgkmcnt(0)" ::: "memory");   // same-wave LDS RAW

    // ---- balanced gather: lane -> outputs j = lane + 50k ----
    if (act) {
#pragma unroll
        for (int k = 0; k < 4; ++k) {
            int j = lane + 50 * k;
            int b = bx[j];
            float wl = cw[b], wr = cw[b + 1];
            float hl = ch[b], hr = ch[b + 1];
            float d0 = dd[b], d1 = dd[b + 1];
            float tau = ((float)j + 0.5f) * (1.f / 200.f);
            float w = wr - wl, h = hr - hl;
            float invw = 1.f / w;
            float delta = h * invw;
            float th = (tau - wl) * invw;
            float t1 = th * (1.f - th);
            float numer = h * fmaf(delta * th, th, d0 * t1);
            float denom = fmaf(d0 + d1 - 2.f * delta, t1, delta);
            orow[j] = hl + numer / denom;
        }
    }
}

// ---------------------------------------------------------------------------
// Fused G3+spline: sp[64 x 640] = X2[64 x 512] @ Wcat^T + bcat, kept in
// LDS/registers only; spline runs in-block; writes out[64 x 200] f32.
// 8 waves 1Mx8N, wave tile 64x80 (acc[4][5]) -> acc[0..1] die after first
// half's scatter (no liveness blowup). B dbuf 80KB; spline panel+tables
// alias the dead B bufs. 2 blocks/CU.
// ---------------------------------------------------------------------------
__global__ __launch_bounds__(512, 4) void gemm_cat_spline(
    const bf16* __restrict__ A, const bf16* __restrict__ W,
    const float* __restrict__ bcat, float* __restrict__ out)
{
    __shared__ __align__(16) char smem[81920];      // B dbuf 2x40K

    const int t = threadIdx.x;
    const int lane = t & 63, wid = t >> 6;
    const int l16 = lane & 15, g16 = lane >> 4;
    const long row0 = (long)blockIdx.x * 64;

    f32x4 acc[4][5];
#pragma unroll
    for (int a = 0; a < 4; ++a)
#pragma unroll
        for (int b = 0; b < 5; ++b) acc[a][b] = (f32x4){0.f, 0.f, 0.f, 0.f};

    auto stageB = [&](int kt, int bi) {     // 40 calls of 1KB: 5 per wave
#pragma unroll
        for (int c = 0; c < 5; ++c) {
            int call = c * 8 + wid;
            int row = call * 16 + (lane >> 2);
            const bf16* src = W + (long)row * 512 + kt * 32 + (lane & 3) * 8;
            async16(src, smem + bi * 40960 + call * 1024);
        }
    };

    const bf16* a0p = A + (row0 + l16) * 512 + g16 * 8;

    stageB(0, 0);
    FENCE();
    bf16x8 af0 = *(const bf16x8*)(a0p);
    bf16x8 af1 = *(const bf16x8*)(a0p + 16 * 512);
    bf16x8 af2 = *(const bf16x8*)(a0p + 32 * 512);
    bf16x8 af3 = *(const bf16x8*)(a0p + 48 * 512);
    asm volatile("s_waitcnt vmcnt(4)\n\ts_barrier" ::: "memory");

    for (int kt = 0; kt < 16; ++kt) {
        const int bi = kt & 1;
        bf16x8 a0 = af0, a1 = af1, a2 = af2, a3 = af3;
        if (kt + 1 < 16) {
            stageB(kt + 1, bi ^ 1);
            FENCE();
            const bf16* ap = a0p + (kt + 1) * 32;
            af0 = *(const bf16x8*)(ap);
            af1 = *(const bf16x8*)(ap + 16 * 512);
            af2 = *(const bf16x8*)(ap + 32 * 512);
            af3 = *(const bf16x8*)(ap + 48 * 512);
        }
        const bf16* Bb = (const bf16*)(smem + bi * 40960);
#pragma unroll
        for (int fn = 0; fn < 5; ++fn) {
            bf16x8 bv = *(const bf16x8*)(Bb + (wid * 80 + fn * 16 + l16) * 32 + g16 * 8);
            acc[0][fn] = MFMA(a0, bv, acc[0][fn], 0, 0, 0);
            acc[1][fn] = MFMA(a1, bv, acc[1][fn], 0, 0, 0);
            acc[2][fn] = MFMA(a2, bv, acc[2][fn], 0, 0, 0);
            acc[3][fn] = MFMA(a3, bv, acc[3][fn], 0, 0, 0);
        }
        if (kt + 1 < 16)
            asm volatile("s_waitcnt vmcnt(4)\n\ts_barrier" ::: "memory");
    }
    __syncthreads();                        // K-loop done; B bufs dead

    // LDS overlays (inside the dead 80KB B region):
    bf16*  spL = (bf16*)smem;               // [32][604] = 38656 B
    float* tab = (float*)(smem + 38912) + wid * 816;   // 8 x 3264 B
    float* abf = (float*)(smem + 65024);    // [64][2] f32 = 512 B

    float bv[5];
#pragma unroll
    for (int fn = 0; fn < 5; ++fn) bv[fn] = bcat[wid * 80 + fn * 16 + l16];

    // a,b (cols 599/600) -> abf as f32 (full precision for exp)
#pragma unroll
    for (int fn = 0; fn < 5; ++fn) {
        int col = wid * 80 + fn * 16 + l16;
        if (col == 599 || col == 600) {
#pragma unroll
            for (int fm = 0; fm < 4; ++fm)
#pragma unroll
                for (int i = 0; i < 4; ++i)
                    abf[(fm * 16 + g16 * 4 + i) * 2 + (col - 599)] = acc[fm][fn][i] + bv[fn];
        }
    }

#pragma unroll
    for (int h = 0; h < 2; ++h) {
        if (h) __syncthreads();             // protect spL/tab from prev reads
        // scatter rows [32h, 32h+32): acc[2h], acc[2h+1]
#pragma unroll
        for (int fm2 = 0; fm2 < 2; ++fm2) {
#pragma unroll
            for (int fn = 0; fn < 5; ++fn) {
                int col = wid * 80 + fn * 16 + l16;
                if (col < 601) {
#pragma unroll
                    for (int i = 0; i < 4; ++i)
                        spL[(fm2 * 16 + g16 * 4 + i) * 604 + col] =
                            (bf16)(acc[2 * h + fm2][fn][i] + bv[fn]);
                }
            }
        }
        __syncthreads();
        // spline: wave wid handles rows wid*4 .. wid*4+3 of this half
#pragma unroll 1
        for (int rr = 0; rr < 4; ++rr) {
            int ridx = wid * 4 + rr;
            int grow = h * 32 + ridx;
            spline_row(spL + ridx * 604, tab,
                       abf[grow * 2 + 0], abf[grow * 2 + 1],
                       out + (size_t)(row0 + grow) * 200, lane);
        }
    }
}

// ---------------------------------------------------------------------------
// Host launcher
// ---------------------------------------------------------------------------
extern "C" void kernel_launch(void* const* d_in, const int* in_sizes, int n_in,
                              void* d_out, int out_size, void* d_ws, size_t ws_size,
                              hipStream_t stream)
{
    const float* inputs = (const float*)d_in[0];
    const float* W1  = (const float*)d_in[1];
    const float* b1  = (const float*)d_in[2];
    const float* g1  = (const float*)d_in[3];
    const float* be1 = (const float*)d_in[4];
    const float* W2  = (const float*)d_in[5];
    const float* b2  = (const float*)d_in[6];
    const float* g2  = (const float*)d_in[7];
    const float* be2 = (const float*)d_in[8];
    const float* WV  = (const float*)d_in[9];
    const float* bV  = (const float*)d_in[10];
    const float* Wa  = (const float*)d_in[11];
    const float* ba  = (const float*)d_in[12];
    const float* Wb  = (const float*)d_in[13];
    const float* bb  = (const float*)d_in[14];
    float* out = (float*)d_out;

    char* ws = (char*)d_ws;
    bf16*  w1b  = (bf16*) (ws + 0);          //   131072
    bf16*  w2b  = (bf16*) (ws + 131072);     //   524288
    bf16*  wcat = (bf16*) (ws + 655360);     //   655360 (640x512)
    float* bcat = (float*)(ws + 1310720);    //     2560 (640 f32)
    bf16*  x    = (bf16*) (ws + 2097152);    // 67108864 (B x 512)
    bf16*  xin  = (bf16*) (ws + 69206016);   // 16777216 (B x 128)

    const int preptot = BATCH * 128 / 8 + 512 * 128 + 512 * 512 + NCAT * 512 + NCAT;
    prep_kernel<<<(preptot + 255) / 256, 256, 0, stream>>>(
        W1, W2, WV, bV, Wa, ba, Wb, bb, inputs, w1b, w2b, wcat, bcat, xin);

    gemm_ln<128><<<BATCH / 128, 1024, 0, stream>>>(xin, w1b, b1, g1, be1, x);
    gemm_ln<512><<<BATCH / 128, 1024, 0, stream>>>(x,   w2b, b2, g2, be2, x);
    gemm_cat_spline<<<BATCH / 64, 512, 0, stream>>>(x, wcat, bcat, out);
}

// Round 9
// 248.786 us; speedup vs baseline: 1.7972x; 1.0609x over previous
//
#include <hip/hip_runtime.h>
#include <stdint.h>

typedef __bf16 bf16;
typedef __bf16 bf16x8 __attribute__((ext_vector_type(8)));
typedef __bf16 bf16x4 __attribute__((ext_vector_type(4)));
typedef float  f32x4  __attribute__((ext_vector_type(4)));
typedef uint32_t u32;

#define BATCH    65536
#define NCAT     640      // 599 spline logits + a + b, padded to 640
#define SPSTRIDE 604      // sp row stride in elements

#define MFMA __builtin_amdgcn_mfma_f32_16x16x32_bf16
#define FENCE() asm volatile("" ::: "memory")

// async global->LDS, 16B per lane; LDS dest = wave-uniform base + lane*16
__device__ __forceinline__ void async16(const void* g, void* l) {
    __builtin_amdgcn_global_load_lds(
        (const u32 __attribute__((address_space(1)))*)g,
        (u32 __attribute__((address_space(3)))*)l,
        16, 0, 0);
}

// ---------------------------------------------------------------------------
// Kernel 0: weights -> bf16; Wcat[640][512] = [WV; Wa; Wb; 0]; inputs -> bf16
// ---------------------------------------------------------------------------
__global__ __launch_bounds__(256) void prep_kernel(
    const float* W1, const float* W2, const float* WV,
    const float* bV, const float* Wa, const float* ba,
    const float* Wb, const float* bb, const float* inputs,
    bf16* w1b, bf16* w2b, bf16* wcat, float* bcat, bf16* xin)
{
    int idx = blockIdx.x * 256 + threadIdx.x;
    const int n1 = 512 * 128, n2 = 512 * 512, n3 = NCAT * 512;
    const int n5 = BATCH * 128 / 8;                 // 8 floats per item
    if (idx < n5) {                                  // input cast (bulk) first
        const float4* src = (const float4*)(inputs + idx * 8);
        float4 v0 = src[0], v1 = src[1];
        bf16x8 h;
        h[0]=(bf16)v0.x; h[1]=(bf16)v0.y; h[2]=(bf16)v0.z; h[3]=(bf16)v0.w;
        h[4]=(bf16)v1.x; h[5]=(bf16)v1.y; h[6]=(bf16)v1.z; h[7]=(bf16)v1.w;
        *(bf16x8*)&xin[idx * 8] = h;
        return;
    }
    idx -= n5;
    if (idx < n1) { w1b[idx] = (bf16)W1[idx]; return; }
    idx -= n1;
    if (idx < n2) { w2b[idx] = (bf16)W2[idx]; return; }
    idx -= n2;
    if (idx < n3) {
        int n = idx >> 9, k = idx & 511;
        float v = 0.f;
        if (n < 599)       v = WV[n * 512 + k];
        else if (n == 599) v = Wa[k];
        else if (n == 600) v = Wb[k];
        wcat[idx] = (bf16)v;
        return;
    }
    idx -= n3;
    if (idx < NCAT) {
        float v = 0.f;
        if (idx < 599)       v = bV[idx];
        else if (idx == 599) v = ba[0];
        else if (idx == 600) v = bb[0];
        bcat[idx] = v;
    }
}

// ---------------------------------------------------------------------------
// G1/G2: C[128 x 512] = A[128 x K] @ W[512 x K]^T + b -> LN -> ReLU -> bf16
// 16 waves 4Mx4N, wave tile 32x128 (acc[2][8]). B: dbuf LDS via
// global_load_lds. A: direct global->VGPR, prefetched 1 step ahead.
// Counted vmcnt(2) + raw s_barrier per K-step (stage drains, A stays flying).
// Output staged in LDS (two 64-row halves) -> dense 16B stores.
// ---------------------------------------------------------------------------
template <int KDIM>
__global__ __launch_bounds__(1024, 4) void gemm_ln(
    const bf16* __restrict__ A, const bf16* __restrict__ W,
    const float* __restrict__ bias, const float* __restrict__ gamma,
    const float* __restrict__ beta, bf16* out)
{
    __shared__ __align__(16) char smem[65536];      // B dbuf 2x32K; stage-out
    __shared__ float Psum[128][4], Psq[128][4];

    const int t = threadIdx.x;
    const int lane = t & 63, wid = t >> 6;
    const int wm = wid >> 2, wn = wid & 3;
    const int l16 = lane & 15, g16 = lane >> 4;
    const long row0 = (long)blockIdx.x * 128;
    constexpr int NT = KDIM / 32;

    const bf16* arow0 = A + (row0 + wm * 32 + l16) * (long)KDIM + g16 * 8;
    const bf16* arow1 = arow0 + 16 * KDIM;

    f32x4 acc[2][8];
#pragma unroll
    for (int a = 0; a < 2; ++a)
#pragma unroll
        for (int b = 0; b < 8; ++b) acc[a][b] = (f32x4){0.f, 0.f, 0.f, 0.f};

    auto stageB = [&](int kt, int bi) {     // 32 calls of 1KB: 2 per wave
#pragma unroll
        for (int c = 0; c < 2; ++c) {
            int call = c * 16 + wid;
            int row = call * 16 + (lane >> 2);
            const bf16* src = W + (long)row * KDIM + kt * 32 + (lane & 3) * 8;
            async16(src, smem + bi * 32768 + call * 1024);
        }
    };

    stageB(0, 0);
    FENCE();
    bf16x8 af0 = *(const bf16x8*)(arow0);
    bf16x8 af1 = *(const bf16x8*)(arow1);
    asm volatile("s_waitcnt vmcnt(2)\n\ts_barrier" ::: "memory");

    for (int kt = 0; kt < NT; ++kt) {
        const int bi = kt & 1;
        bf16x8 a0 = af0, a1 = af1;
        if (kt + 1 < NT) {
            stageB(kt + 1, bi ^ 1);
            FENCE();
            af0 = *(const bf16x8*)(arow0 + (kt + 1) * 32);
            af1 = *(const bf16x8*)(arow1 + (kt + 1) * 32);
        }
        const bf16* Bb = (const bf16*)(smem + bi * 32768);
#pragma unroll
        for (int fn = 0; fn < 8; ++fn) {
            bf16x8 bv = *(const bf16x8*)(Bb + (wn * 128 + fn * 16 + l16) * 32 + g16 * 8);
            acc[0][fn] = MFMA(a0, bv, acc[0][fn], 0, 0, 0);
            acc[1][fn] = MFMA(a1, bv, acc[1][fn], 0, 0, 0);
        }
        if (kt + 1 < NT)
            asm volatile("s_waitcnt vmcnt(2)\n\ts_barrier" ::: "memory");
    }

    // ---- epilogue: +bias, LN over 512, ReLU -> two-half staged writeout ----
    float gv[8], bev[8];
#pragma unroll
    for (int fn = 0; fn < 8; ++fn) {
        int col = wn * 128 + fn * 16 + l16;
        float bv = bias[col];
        gv[fn] = gamma[col]; bev[fn] = beta[col];
#pragma unroll
        for (int fm = 0; fm < 2; ++fm)
#pragma unroll
            for (int i = 0; i < 4; ++i) acc[fm][fn][i] += bv;
    }
#pragma unroll
    for (int fm = 0; fm < 2; ++fm)
#pragma unroll
        for (int i = 0; i < 4; ++i) {
            float s = 0.f, q = 0.f;
#pragma unroll
            for (int fn = 0; fn < 8; ++fn) { float v = acc[fm][fn][i]; s += v; q += v * v; }
#pragma unroll
            for (int m = 1; m < 16; m <<= 1) { s += __shfl_xor(s, m); q += __shfl_xor(q, m); }
            if (l16 == 0) {
                int lr = wm * 32 + fm * 16 + g16 * 4 + i;
                Psum[lr][wn] = s; Psq[lr][wn] = q;
            }
        }
    __syncthreads();
    float mmean[2][4], mrstd[2][4];
#pragma unroll
    for (int fm = 0; fm < 2; ++fm)
#pragma unroll
        for (int i = 0; i < 4; ++i) {
            int lr = wm * 32 + fm * 16 + g16 * 4 + i;
            float s = Psum[lr][0] + Psum[lr][1] + Psum[lr][2] + Psum[lr][3];
            float q = Psq[lr][0] + Psq[lr][1] + Psq[lr][2] + Psq[lr][3];
            float mean = s * (1.f / 512.f);
            float var  = q * (1.f / 512.f) - mean * mean;
            mmean[fm][i] = mean;
            mrstd[fm][i] = rsqrtf(var + 1e-5f);
        }
    bf16* stg = (bf16*)smem;
#pragma unroll
    for (int h = 0; h < 2; ++h) {
        __syncthreads();
#pragma unroll
        for (int fm = 0; fm < 2; ++fm)
#pragma unroll
            for (int i = 0; i < 4; ++i) {
                int lr = wm * 32 + fm * 16 + g16 * 4 + i;
                if ((lr >> 6) != h) continue;
#pragma unroll
                for (int fn = 0; fn < 8; ++fn) {
                    int col = wn * 128 + fn * 16 + l16;
                    float o = (acc[fm][fn][i] - mmean[fm][i]) * mrstd[fm][i] * gv[fn] + bev[fn];
                    stg[(lr & 63) * 512 + col] = (bf16)fmaxf(o, 0.f);
                }
            }
        __syncthreads();
#pragma unroll
        for (int it = 0; it < 4; ++it) {          // 64 rows x 1KB dense
            int idx = it * 1024 + t;
            *(bf16x8*)&out[(row0 + h * 64 + (idx >> 6)) * 512 + (idx & 63) * 8] =
                *(const bf16x8*)&stg[idx * 8];
        }
    }
}

// ---------------------------------------------------------------------------
// G3: sp[128 x 640] = X2[128 x 512] @ Wcat^T + bcat.
// Mirror of gemm_ln's proven loop: 16 waves 4Mx4N, wave tile 32x160
// (acc[2][10]); B dbuf + global_load_lds; A direct depth-1 prefetch;
// counted vmcnt(2) + raw barrier. Two-half staged dense sp writeout.
// ---------------------------------------------------------------------------
__global__ __launch_bounds__(1024, 4) void gemm_cat(
    const bf16* __restrict__ A, const bf16* __restrict__ W,
    const float* __restrict__ bcat, bf16* __restrict__ sp, float* __restrict__ ab)
{
    __shared__ __align__(16) char smem[81920];      // B dbuf 2x40K; stage-out

    const int t = threadIdx.x;
    const int lane = t & 63, wid = t >> 6;
    const int wm = wid >> 2, wn = wid & 3;
    const int l16 = lane & 15, g16 = lane >> 4;
    const long row0 = (long)blockIdx.x * 128;

    const bf16* arow0 = A + (row0 + wm * 32 + l16) * 512 + g16 * 8;
    const bf16* arow1 = arow0 + 16 * 512;

    f32x4 acc[2][10];
#pragma unroll
    for (int a = 0; a < 2; ++a)
#pragma unroll
        for (int b = 0; b < 10; ++b) acc[a][b] = (f32x4){0.f, 0.f, 0.f, 0.f};

    auto stageB = [&](int kt, int bi) {     // 40 calls of 1KB
#pragma unroll
        for (int c = 0; c < 3; ++c) {
            int call = c * 16 + wid;
            if (call < 40) {
                int row = call * 16 + (lane >> 2);
                const bf16* src = W + (long)row * 512 + kt * 32 + (lane & 3) * 8;
                async16(src, smem + bi * 40960 + call * 1024);
            }
        }
    };

    stageB(0, 0);
    FENCE();
    bf16x8 af0 = *(const bf16x8*)(arow0);
    bf16x8 af1 = *(const bf16x8*)(arow1);
    asm volatile("s_waitcnt vmcnt(2)\n\ts_barrier" ::: "memory");

    for (int kt = 0; kt < 16; ++kt) {
        const int bi = kt & 1;
        bf16x8 a0 = af0, a1 = af1;
        if (kt + 1 < 16) {
            stageB(kt + 1, bi ^ 1);
            FENCE();
            af0 = *(const bf16x8*)(arow0 + (kt + 1) * 32);
            af1 = *(const bf16x8*)(arow1 + (kt + 1) * 32);
        }
        const bf16* Bb = (const bf16*)(smem + bi * 40960);
#pragma unroll
        for (int fn = 0; fn < 10; ++fn) {
            bf16x8 bv = *(const bf16x8*)(Bb + (wn * 160 + fn * 16 + l16) * 32 + g16 * 8);
            acc[0][fn] = MFMA(a0, bv, acc[0][fn], 0, 0, 0);
            acc[1][fn] = MFMA(a1, bv, acc[1][fn], 0, 0, 0);
        }
        if (kt + 1 < 16)
            asm volatile("s_waitcnt vmcnt(2)\n\ts_barrier" ::: "memory");
    }
    __syncthreads();                        // drain; B bufs dead

    // ---- +bcat; ab f32 direct; two-half staged dense writeout ----
    float bv[10];
#pragma unroll
    for (int fn = 0; fn < 10; ++fn) bv[fn] = bcat[wn * 160 + fn * 16 + l16];

#pragma unroll
    for (int fn = 0; fn < 10; ++fn) {
        int col = wn * 160 + fn * 16 + l16;
        if (col == 599 || col == 600) {
#pragma unroll
            for (int fm = 0; fm < 2; ++fm)
#pragma unroll
                for (int i = 0; i < 4; ++i) {
                    int lr = wm * 32 + fm * 16 + g16 * 4 + i;
                    ab[(row0 + lr) * 2 + (col - 599)] = acc[fm][fn][i] + bv[fn];
                }
        }
    }

    bf16* stg = (bf16*)smem;
#pragma unroll
    for (int h = 0; h < 2; ++h) {
        __syncthreads();
#pragma unroll
        for (int fn = 0; fn < 10; ++fn) {
            int col = wn * 160 + fn * 16 + l16;
            if (col >= SPSTRIDE) continue;
#pragma unroll
            for (int fm = 0; fm < 2; ++fm)
#pragma unroll
                for (int i = 0; i < 4; ++i) {
                    int lr = wm * 32 + fm * 16 + g16 * 4 + i;
                    if ((lr >> 6) != h) continue;
                    stg[(lr & 63) * SPSTRIDE + col] = (bf16)(acc[fm][fn][i] + bv[fn]);
                }
        }
        __syncthreads();
#pragma unroll
        for (int it = 0; it < 10; ++it) {         // 64 rows x 151 8B-chunks
            int c = it * 1024 + t;
            if (c < 64 * 151) {
                int r = c / 151, k = c - r * 151;
                *(uint64_t*)&sp[(row0 + h * 64 + r) * SPSTRIDE + k * 4] =
                    *(const uint64_t*)&stg[r * SPSTRIDE + k * 4];
            }
        }
    }
}

// ---------------------------------------------------------------------------
// Spline v3 (standalone, proven): register scan -> LDS param tables ->
// binidx scatter -> balanced gather (lane computes 4 outputs j = lane + 50k).
// One wave per row, 4 rows/block, high occupancy.
// ---------------------------------------------------------------------------
__global__ __launch_bounds__(256) void spline_kernel(
    const bf16* __restrict__ sp, const float* __restrict__ ab, float* __restrict__ out)
{
    __shared__ float S[4][816];     // per wave: cw@0, ch@204, dd@408, binidx@612
    const int t = threadIdx.x;
    const int lane = t & 63, wid = t >> 6;
    const long row = (long)blockIdx.x * 4 + wid;
    const bf16* spr = sp + row * SPSTRIDE;
    const bool act = lane < 50;
    const float EC = 0.53974247f;                 // log(exp(0.999)-1)
    float* cw = &S[wid][0];
    float* ch = &S[wid][204];
    float* dd = &S[wid][408];
    int*   bx = (int*)&S[wid][612];

    const float sa = __expf(ab[row * 2 + 0]);
    const float sb = ab[row * 2 + 1];

    auto rng = [](float x) -> int {               // first j with tau_j >= x
        int v = (int)ceilf(fmaf(200.f, x, -0.5f));
        return v < 0 ? 0 : (v > 200 ? 200 : v);
    };

    // ---- W logits -> widths -> cw[4l..4l+3] in regs ----
    float p0, p1, p2, p3;
    {
        float x0, x1, x2v, x3;
        if (act) {
            bf16x4 v = *(const bf16x4*)&spr[4 * lane];
            x0 = (float)v[0]; x1 = (float)v[1]; x2v = (float)v[2]; x3 = (float)v[3];
        } else { x0 = x1 = x2v = x3 = -1e30f; }
        float m = fmaxf(fmaxf(x0, x1), fmaxf(x2v, x3));
#pragma unroll
        for (int d = 1; d < 64; d <<= 1) m = fmaxf(m, __shfl_xor(m, d));
        float e0 = act ? __expf(x0 - m) : 0.f;
        float e1 = act ? __expf(x1 - m) : 0.f;
        float e2 = act ? __expf(x2v - m) : 0.f;
        float e3 = act ? __expf(x3 - m) : 0.f;
        float s = e0 + e1 + e2 + e3;
#pragma unroll
        for (int d = 1; d < 64; d <<= 1) s += __shfl_xor(s, d);
        float inv = 0.8f / s;
        p0 = act ? fmaf(e0, inv, 0.001f) : 0.f;
        p1 = act ? fmaf(e1, inv, 0.001f) : 0.f;
        p2 = act ? fmaf(e2, inv, 0.001f) : 0.f;
        p3 = act ? fmaf(e3, inv, 0.001f) : 0.f;
    }
    float c0 = p0, c1 = c0 + p1, c2 = c1 + p2, c3 = c2 + p3;
    float run = c3, ts = run;
#pragma unroll
    for (int d = 1; d < 64; d <<= 1) { float u = __shfl_up(ts, d); if (lane >= d) ts += u; }
    float excl  = ts - run;
    float nexcl = __shfl_down(excl, 1);
    float cwl0 = excl, cwl1 = excl + c0, cwl2 = excl + c1, cwl3 = excl + c2;

    // ---- H logits -> heights -> ch[4l..4l+3] ----
    float hp0, hp1, hp2, hp3;
    {
        float x0, x1, x2v, x3;
        if (act) {
            bf16x4 v = *(const bf16x4*)&spr[200 + 4 * lane];
            x0 = (float)v[0]; x1 = (float)v[1]; x2v = (float)v[2]; x3 = (float)v[3];
        } else { x0 = x1 = x2v = x3 = -1e30f; }
        float m = fmaxf(fmaxf(x0, x1), fmaxf(x2v, x3));
#pragma unroll
        for (int d = 1; d < 64; d <<= 1) m = fmaxf(m, __shfl_xor(m, d));
        float e0 = act ? __expf(x0 - m) : 0.f;
        float e1 = act ? __expf(x1 - m) : 0.f;
        float e2 = act ? __expf(x2v - m) : 0.f;
        float e3 = act ? __expf(x3 - m) : 0.f;
        float s = e0 + e1 + e2 + e3;
#pragma unroll
        for (int d = 1; d < 64; d <<= 1) s += __shfl_xor(s, d);
        float inv = 0.8f / s;
        hp0 = act ? fmaf(e0, inv, 0.001f) : 0.f;
        hp1 = act ? fmaf(e1, inv, 0.001f) : 0.f;
        hp2 = act ? fmaf(e2, inv, 0.001f) : 0.f;
        hp3 = act ? fmaf(e3, inv, 0.001f) : 0.f;
    }
    float hc0 = hp0, hc1 = hc0 + hp1, hc2 = hc1 + hp2, hc3 = hc2 + hp3;
    float hrun = hc3, hts = hrun;
#pragma unroll
    for (int d = 1; d < 64; d <<= 1) { float u = __shfl_up(hts, d); if (lane >= d) hts += u; }
    float hexcl = hts - hrun;
    float ch0 = fmaf(sa, hexcl, sb);
    float ch1 = fmaf(sa, hexcl + hc0, sb);
    float ch2 = fmaf(sa, hexcl + hc1, sb);
    float ch3 = fmaf(sa, hexcl + hc2, sb);

    // ---- D (softplus): dd[4l..4l+3] = {dprev, dv0, dv1, dv2} ----
    float dv0, dv1, dv2, dv3;
    {
        float x0 = 0.f, x1 = 0.f, x2v = 0.f, x3 = 0.f;
        if (act) {
            bf16x4 v = *(const bf16x4*)&spr[400 + 4 * lane];
            x0 = (float)v[0]; x1 = (float)v[1]; x2v = (float)v[2]; x3 = (float)v[3];
        }
        auto spls = [](float x) {
            return fmaxf(x, 0.f) + __logf(1.f + __expf(-fabsf(x))) + 0.001f;
        };
        dv0 = spls(x0); dv1 = spls(x1); dv2 = spls(x2v); dv3 = spls(x3);
    }
    if (lane == 49) dv3 = EC;                     // dd[200] = EDGE
    float dprev = __shfl_up(dv3, 1);
    if (lane == 0) dprev = EC;                    // dd[0] = EDGE

    // ---- write param tables (aligned 16B stores) + tails ----
    if (act) {
        *(f32x4*)&cw[4 * lane] = (f32x4){cwl0, cwl1, cwl2, cwl3};
        *(f32x4*)&ch[4 * lane] = (f32x4){ch0, ch1, ch2, ch3};
        *(f32x4*)&dd[4 * lane] = (f32x4){dprev, dv0, dv1, dv2};
    }
    if (lane == 49) {
        cw[200] = 1.0f;                           // cw[:, -1].set(1.0)
        ch[200] = fmaf(sa, hts, sb);              // sa * total + sb
        dd[200] = EC;
    }

    // ---- scatter bin indices (tiny body; exact partition of [0,200)) ----
    if (act) {
        int b0 = rng(cwl0), b1 = rng(cwl1), b2 = rng(cwl2), b3 = rng(cwl3);
        int b4 = (lane == 49) ? 200 : rng(nexcl);
        for (int j = b0; j < b1; ++j) bx[j] = 4 * lane;
        for (int j = b1; j < b2; ++j) bx[j] = 4 * lane + 1;
        for (int j = b2; j < b3; ++j) bx[j] = 4 * lane + 2;
        for (int j = b3; j < b4; ++j) bx[j] = 4 * lane + 3;
    }
    asm volatile("s_waitcnt lgkmcnt(0)" ::: "memory");   // same-wave LDS RAW

    // ---- balanced gather: lane -> outputs j = lane + 50k ----
    if (act) {
        float* orow = out + (size_t)row * 200;
#pragma unroll
        for (int k = 0; k < 4; ++k) {
            int j = lane + 50 * k;
            int b = bx[j];
            float wl = cw[b], wr = cw[b + 1];
            float hl = ch[b], hr = ch[b + 1];
            float d0 = dd[b], d1 = dd[b + 1];
            float tau = ((float)j + 0.5f) * (1.f / 200.f);
            float w = wr - wl, h = hr - hl;
            float invw = 1.f / w;
            float delta = h * invw;
            float th = (tau - wl) * invw;
            float t1 = th * (1.f - th);
            float numer = h * fmaf(delta * th, th, d0 * t1);
            float denom = fmaf(d0 + d1 - 2.f * delta, t1, delta);
            orow[j] = hl + numer / denom;
        }
    }
}

// ---------------------------------------------------------------------------
// Host launcher
// ---------------------------------------------------------------------------
extern "C" void kernel_launch(void* const* d_in, const int* in_sizes, int n_in,
                              void* d_out, int out_size, void* d_ws, size_t ws_size,
                              hipStream_t stream)
{
    const float* inputs = (const float*)d_in[0];
    const float* W1  = (const float*)d_in[1];
    const float* b1  = (const float*)d_in[2];
    const float* g1  = (const float*)d_in[3];
    const float* be1 = (const float*)d_in[4];
    const float* W2  = (const float*)d_in[5];
    const float* b2  = (const float*)d_in[6];
    const float* g2  = (const float*)d_in[7];
    const float* be2 = (const float*)d_in[8];
    const float* WV  = (const float*)d_in[9];
    const float* bV  = (const float*)d_in[10];
    const float* Wa  = (const float*)d_in[11];
    const float* ba  = (const float*)d_in[12];
    const float* Wb  = (const float*)d_in[13];
    const float* bb  = (const float*)d_in[14];
    float* out = (float*)d_out;

    char* ws = (char*)d_ws;
    bf16*  w1b  = (bf16*) (ws + 0);          //   131072
    bf16*  w2b  = (bf16*) (ws + 131072);     //   524288
    bf16*  wcat = (bf16*) (ws + 655360);     //   655360 (640x512)
    float* bcat = (float*)(ws + 1310720);    //     2560 (640 f32)
    float* ab   = (float*)(ws + 1313280);    //   524288 (B x 2)
    bf16*  x    = (bf16*) (ws + 2097152);    // 67108864 (B x 512)
    bf16*  spb  = (bf16*) (ws + 69206016);   // 79167488 (B x 604)
    bf16*  xin  = (bf16*) (ws + 69206016);   // 16777216 (B x 128) — dead before G3 writes spb

    const int preptot = BATCH * 128 / 8 + 512 * 128 + 512 * 512 + NCAT * 512 + NCAT;
    prep_kernel<<<(preptot + 255) / 256, 256, 0, stream>>>(
        W1, W2, WV, bV, Wa, ba, Wb, bb, inputs, w1b, w2b, wcat, bcat, xin);

    gemm_ln<128><<<BATCH / 128, 1024, 0, stream>>>(xin, w1b, b1, g1, be1, x);
    gemm_ln<512><<<BATCH / 128, 1024, 0, stream>>>(x,   w2b, b2, g2, be2, x);
    gemm_cat<<<BATCH / 128, 1024, 0, stream>>>(x, wcat, bcat, spb, ab);
    spline_kernel<<<BATCH / 4, 256, 0, stream>>>(spb, ab, out);
}